// Round 4
// baseline (421.157 us; speedup 1.0000x reference)
//
#include <hip/hip_runtime.h>
#include <hip/hip_bf16.h>

#define N_PTS 50000
#define NNB   32
#define KP    15
#define DIN   64
#define DOUT  1024
#define KDIM  (KP*DIN)    // 960
#define NB    16
#define SIGMA_INV (1.0f/0.3f)

#define BM 256
#define BN 256
#define BK 64
#define NKT (KDIM/BK)              // 15
#define RB ((N_PTS + BM - 1)/BM)   // 196 row blocks
#define M_PAD (RB*BM)              // 50176

typedef __attribute__((ext_vector_type(8))) short bf16x8;
typedef __attribute__((ext_vector_type(4))) float f32x4;

#define GLD16(gsrc, ldst) \
  __builtin_amdgcn_global_load_lds((const __attribute__((address_space(1))) char*)(gsrc), \
                                   (__attribute__((address_space(3))) char*)(ldst), 16, 0, 0)

// ---------------- Kernel 0: W [960][1024] f32 -> Wt [1024][960] bf16 ---------
__global__ __launch_bounds__(256) void wt_kernel(
    const float* __restrict__ W, __hip_bfloat16* __restrict__ Wt) {
  __shared__ float t[64][65];
  int k0 = blockIdx.x * 64;   // 15
  int o0 = blockIdx.y * 64;   // 16
  int tx = threadIdx.x & 63, ty = threadIdx.x >> 6;
  for (int r = ty; r < 64; r += 4) t[r][tx] = W[(size_t)(k0 + r)*DOUT + o0 + tx];
  __syncthreads();
  for (int r = ty; r < 64; r += 4)
    Wt[(size_t)(o0 + r)*KDIM + k0 + tx] = __float2bfloat16(t[tx][r]);
}

// ---------------- Kernel 1: KPConv g rows, one WAVE per point ---------------
__global__ __launch_bounds__(256) void kpconv_wave_kernel(
    const float* __restrict__ pos, const float* __restrict__ feats,
    const float* __restrict__ kpts, const int* __restrict__ nidx,
    __hip_bfloat16* __restrict__ g) {
  __shared__ float h_lds[4][NNB][16];
  int tid = threadIdx.x;
  int w = tid >> 6, lane = tid & 63;
  int n = blockIdx.x * 4 + w;
  float acc[KP];
  #pragma unroll
  for (int k = 0; k < KP; ++k) acc[k] = 0.0f;

  if (n < N_PTS) {
    int myj = lane & 31;
    int id0 = nidx[n*NNB + myj];
    float px = pos[n*3+0], py = pos[n*3+1], pz = pos[n*3+2];
    float rx = pos[id0*3+0] - px;
    float ry = pos[id0*3+1] - py;
    float rz = pos[id0*3+2] - pz;
    bool anyact = false;
    int khalf = lane >> 5;
    #pragma unroll
    for (int i = 0; i < 8; ++i) {
      int k = 2*i + khalf;
      if (k < KP) {
        float dx = rx - kpts[k*3+0];
        float dy = ry - kpts[k*3+1];
        float dz = rz - kpts[k*3+2];
        float d = sqrtf(dx*dx + dy*dy + dz*dz);
        float h = 1.0f - d * SIGMA_INV;
        h = h > 0.0f ? h : 0.0f;
        h_lds[w][myj][k] = h;
        anyact |= (h > 0.0f);
      }
    }
    unsigned long long bal = __ballot(anyact);
    unsigned int actj = (unsigned int)(bal | (bal >> 32));
    while (actj) {
      int j = __ffs(actj) - 1;
      actj &= actj - 1;
      int id = __shfl(id0, j);
      float f = feats[(size_t)id*DIN + lane];
      #pragma unroll
      for (int k = 0; k < KP; ++k) acc[k] += h_lds[w][j][k] * f;
    }
  }
  if (n < M_PAD) {
    size_t base = (size_t)n*KDIM;
    #pragma unroll
    for (int k = 0; k < KP; ++k)
      g[base + k*DIN + lane] = __float2bfloat16(acc[k]);
  }
}

// ---------------- Kernel 2: 256x256 MFMA GEMM (2-phase) + fused pool ---------
__global__ __launch_bounds__(512) void gemm256_pool(
    const __hip_bfloat16* __restrict__ g, const __hip_bfloat16* __restrict__ Wt,
    const int* __restrict__ batch, float* __restrict__ partial) {
  __shared__ __align__(16) char lds[2*65536];   // [buf][A 32KB | B 32KB]
  __shared__ float psum[NB][BN];
  __shared__ int bid[BM];
  int cb = blockIdx.x, rb = blockIdx.y;
  int r0 = rb*BM, c0 = cb*BN;
  int tid = threadIdx.x;
  int lane = tid & 63, w = tid >> 6;
  int wr = w >> 2, wc = w & 3;

  f32x4 acc[8][4] = {};   // acc[m][n], rows wr*128+m*16.., cols wc*64+n*16..

  #define STAGE(kt, buf) do {                                                  \
    char* dA = lds + (buf)*65536;                                              \
    char* dB = dA + 32768;                                                     \
    size_t kk0 = (size_t)(kt)*BK;                                              \
    _Pragma("unroll")                                                          \
    for (int i = 0; i < 4; ++i) {                                              \
      int e = i*512 + tid;                                                     \
      int row = e >> 3, ch = e & 7;                                            \
      GLD16(g  + (size_t)(r0+row)*KDIM + kk0 + ch*8, dA + e*16);               \
    }                                                                          \
    _Pragma("unroll")                                                          \
    for (int i = 0; i < 4; ++i) {                                              \
      int e = i*512 + tid;                                                     \
      int row = e >> 3, ch = e & 7;                                            \
      GLD16(Wt + (size_t)(c0+row)*KDIM + kk0 + ch*8, dB + e*16);               \
    }                                                                          \
  } while (0)

  STAGE(0, 0);
  __syncthreads();
  for (int kt = 0; kt < NKT; ++kt) {
    int buf = kt & 1;
    if (kt + 1 < NKT) STAGE(kt + 1, buf ^ 1);
    const char* A = lds + buf*65536;
    const char* B = A + 32768;
    #pragma unroll
    for (int ks = 0; ks < 2; ++ks) {
      bf16x8 af[8], bfr[4];
      #pragma unroll
      for (int m = 0; m < 8; ++m) {
        int row = wr*128 + m*16 + (lane & 15);
        af[m] = *(const bf16x8*)(A + row*128 + ks*64 + (lane >> 4)*16);   // ks*64: each MFMA eats 32 bf16 = 64B
      }
      #pragma unroll
      for (int n = 0; n < 4; ++n) {
        int row = wc*64 + n*16 + (lane & 15);
        bfr[n] = *(const bf16x8*)(B + row*128 + ks*64 + (lane >> 4)*16);
      }
      #pragma unroll
      for (int m = 0; m < 8; ++m)
        #pragma unroll
        for (int n = 0; n < 4; ++n)
          acc[m][n] = __builtin_amdgcn_mfma_f32_16x16x32_bf16(af[m], bfr[n], acc[m][n], 0, 0, 0);
    }
    __syncthreads();   // drains vmcnt (stage done) + all reads of buf done
  }

  // ---- epilogue: leaky + deterministic per-batch column sums ----
  if (tid < BM) bid[tid] = (r0 + tid < N_PTS) ? batch[r0 + tid] : -1;
  for (int z = tid; z < NB*BN; z += 512) (&psum[0][0])[z] = 0.0f;
  __syncthreads();
  int q = lane >> 4;
  #pragma unroll 1
  for (int phase = 0; phase < 8; ++phase) {
    if (wr*4 + q == phase) {
      #pragma unroll
      for (int n = 0; n < 4; ++n) {
        int c = wc*64 + n*16 + (lane & 15);
        float run = 0.0f; int curb = -2;
        #pragma unroll
        for (int m = 0; m < 8; ++m) {
          #pragma unroll
          for (int j = 0; j < 4; ++j) {
            int r = wr*128 + m*16 + q*4 + j;
            int b = bid[r];
            float v = acc[m][n][j];
            v = v > 0.0f ? v : 0.1f*v;
            if (b != curb) { if (curb >= 0) psum[curb][c] += run; run = 0.0f; curb = b; }
            run += v;
          }
        }
        if (curb >= 0) psum[curb][c] += run;
      }
    }
    __syncthreads();
  }
  for (int z = tid; z < NB*BN; z += 512) {
    int b = z >> 8, c = z & 255;
    partial[((size_t)rb*NB + b)*DOUT + c0 + c] = psum[b][c];
  }
}

// ---------------- Kernel 3: reduce partials -> pooled mean -------------------
__global__ __launch_bounds__(256) void reduce_pool_kernel(
    const float* __restrict__ partial, const int* __restrict__ batch,
    float* __restrict__ pooled) {
  int b = blockIdx.y;
  int c = blockIdx.x*256 + threadIdx.x;
  float s0=0.f, s1=0.f, s2=0.f, s3=0.f;
  int rb = 0;
  for (; rb + 4 <= RB; rb += 4) {
    s0 += partial[((size_t)(rb+0)*NB + b)*DOUT + c];
    s1 += partial[((size_t)(rb+1)*NB + b)*DOUT + c];
    s2 += partial[((size_t)(rb+2)*NB + b)*DOUT + c];
    s3 += partial[((size_t)(rb+3)*NB + b)*DOUT + c];
  }
  for (; rb < RB; ++rb) s0 += partial[((size_t)rb*NB + b)*DOUT + c];
  float s = (s0+s1)+(s2+s3);
  int lb, ub;
  { int l = 0, r = N_PTS; while (l < r) { int m = (l+r)>>1; if (batch[m] <  b) l = m+1; else r = m; } lb = l; }
  { int l = 0, r = N_PTS; while (l < r) { int m = (l+r)>>1; if (batch[m] <= b) l = m+1; else r = m; } ub = l; }
  float cnt = (float)(ub - lb);
  pooled[b*DOUT + c] = s / fmaxf(cnt, 1.0f);
}

// ---------------- Kernel 4: fused 3-layer MLP head --------------------------
__global__ __launch_bounds__(512) void mlp_fused_kernel(
    const float* __restrict__ pooled,
    const float* __restrict__ w1, const float* __restrict__ b1,
    const float* __restrict__ w2, const float* __restrict__ b2,
    const float* __restrict__ w3, const float* __restrict__ b3,
    float* __restrict__ out) {
  __shared__ float pl[DOUT];    // pooled row, later reused for h2
  __shared__ float hh[512];     // h1
  int b = blockIdx.x, o = threadIdx.x;
  for (int i = o; i < DOUT; i += 512) pl[i] = pooled[b*DOUT + i];
  __syncthreads();
  float a = b1[o];
  #pragma unroll 8
  for (int i = 0; i < DOUT; ++i) a += pl[i] * w1[(size_t)i*512 + o];
  hh[o] = fmaxf(a, 0.0f);
  __syncthreads();
  float a2 = 0.0f;
  if (o < 256) {
    a2 = b2[o];
    #pragma unroll 8
    for (int i = 0; i < 512; ++i) a2 += hh[i] * w2[(size_t)i*256 + o];
  }
  __syncthreads();
  if (o < 256) pl[o] = fmaxf(a2, 0.0f);
  __syncthreads();
  if (o < 152) {
    float a3 = b3[o];
    #pragma unroll 8
    for (int i = 0; i < 256; ++i) a3 += pl[i] * w3[i*152 + o];
    out[b*152 + o] = a3;
  }
}

// ---------------- launch -----------------------------------------------------
extern "C" void kernel_launch(void* const* d_in, const int* in_sizes, int n_in,
                              void* d_out, int out_size, void* d_ws, size_t ws_size,
                              hipStream_t stream) {
  (void)in_sizes; (void)n_in; (void)out_size; (void)ws_size;
  const float* pos   = (const float*)d_in[0];
  const float* feats = (const float*)d_in[1];
  const float* kpts  = (const float*)d_in[2];
  const float* kpw   = (const float*)d_in[3];
  const float* w1    = (const float*)d_in[4];
  const float* b1    = (const float*)d_in[5];
  const float* w2    = (const float*)d_in[6];
  const float* b2    = (const float*)d_in[7];
  const float* w3    = (const float*)d_in[8];
  const float* b3    = (const float*)d_in[9];
  const int* nidx    = (const int*)d_in[10];
  const int* batch   = (const int*)d_in[11];
  float* out = (float*)d_out;

  char* ws = (char*)d_ws;
  const size_t off_g       = 0;                          // 50176*960*2   = 96,337,920
  const size_t off_wt      = 96337920;                   // 1024*960*2    = 1,966,080
  const size_t off_partial = off_wt + 1966080;           // 196*16*1024*4 = 12,845,056
  const size_t off_pooled  = off_partial + 12845056;     // 65,536
  __hip_bfloat16* g  = (__hip_bfloat16*)(ws + off_g);
  __hip_bfloat16* wt = (__hip_bfloat16*)(ws + off_wt);
  float* partial = (float*)(ws + off_partial);
  float* pooled  = (float*)(ws + off_pooled);

  wt_kernel<<<dim3(KDIM/64, DOUT/64), 256, 0, stream>>>(kpw, wt);
  kpconv_wave_kernel<<<M_PAD/4, 256, 0, stream>>>(pos, feats, kpts, nidx, g);
  gemm256_pool<<<dim3(DOUT/BN, RB), 512, 0, stream>>>(g, wt, batch, partial);
  reduce_pool_kernel<<<dim3(DOUT/256, NB), 256, 0, stream>>>(partial, batch, pooled);
  mlp_fused_kernel<<<NB, 512, 0, stream>>>(pooled, w1, b1, w2, b2, w3, b3, out);
}

// Round 5
// 393.146 us; speedup vs baseline: 1.0712x; 1.0712x over previous
//
#include <hip/hip_runtime.h>
#include <hip/hip_bf16.h>

#define N_PTS 50000
#define NNB   32
#define KP    15
#define DIN   64
#define DOUT  1024
#define KDIM  (KP*DIN)    // 960
#define NB    16
#define SIGMA_INV (1.0f/0.3f)

#define BM 128
#define BN 128
#define BK 64
#define NKT (KDIM/BK)              // 15
#define RB ((N_PTS + BM - 1)/BM)   // 391 -> pad to 392 for XCD swizzle
#define RBP 392
#define M_PAD (RBP*BM)             // 50176
#define NCB (DOUT/BN)              // 8
#define NWG (RBP*NCB)              // 3136, %8 == 0

typedef __attribute__((ext_vector_type(8))) short bf16x8;
typedef __attribute__((ext_vector_type(4))) float f32x4;

#define GLD16(gsrc, ldst) \
  __builtin_amdgcn_global_load_lds((const __attribute__((address_space(1))) char*)(gsrc), \
                                   (__attribute__((address_space(3))) char*)(ldst), 16, 0, 0)

// ---------------- Kernel 0: W [960][1024] f32 -> Wt [1024][960] bf16 ---------
__global__ __launch_bounds__(256) void wt_kernel(
    const float* __restrict__ W, __hip_bfloat16* __restrict__ Wt) {
  __shared__ float t[64][65];
  int k0 = blockIdx.x * 64;
  int o0 = blockIdx.y * 64;
  int tx = threadIdx.x & 63, ty = threadIdx.x >> 6;
  for (int r = ty; r < 64; r += 4) t[r][tx] = W[(size_t)(k0 + r)*DOUT + o0 + tx];
  __syncthreads();
  for (int r = ty; r < 64; r += 4)
    Wt[(size_t)(o0 + r)*KDIM + k0 + tx] = __float2bfloat16(t[tx][r]);
}

// ---------------- Kernel 1: KPConv g rows, one WAVE per point ---------------
__global__ __launch_bounds__(256) void kpconv_wave_kernel(
    const float* __restrict__ pos, const float* __restrict__ feats,
    const float* __restrict__ kpts, const int* __restrict__ nidx,
    __hip_bfloat16* __restrict__ g) {
  __shared__ float h_lds[4][NNB][16];
  int tid = threadIdx.x;
  int w = tid >> 6, lane = tid & 63;
  int n = blockIdx.x * 4 + w;
  float acc[KP];
  #pragma unroll
  for (int k = 0; k < KP; ++k) acc[k] = 0.0f;

  if (n < N_PTS) {
    int myj = lane & 31;
    int id0 = nidx[n*NNB + myj];
    float px = pos[n*3+0], py = pos[n*3+1], pz = pos[n*3+2];
    float rx = pos[id0*3+0] - px;
    float ry = pos[id0*3+1] - py;
    float rz = pos[id0*3+2] - pz;
    bool anyact = false;
    int khalf = lane >> 5;
    #pragma unroll
    for (int i = 0; i < 8; ++i) {
      int k = 2*i + khalf;
      if (k < KP) {
        float dx = rx - kpts[k*3+0];
        float dy = ry - kpts[k*3+1];
        float dz = rz - kpts[k*3+2];
        float d = sqrtf(dx*dx + dy*dy + dz*dz);
        float h = 1.0f - d * SIGMA_INV;
        h = h > 0.0f ? h : 0.0f;
        h_lds[w][myj][k] = h;
        anyact |= (h > 0.0f);
      }
    }
    unsigned long long bal = __ballot(anyact);
    unsigned int actj = (unsigned int)(bal | (bal >> 32));
    while (actj) {
      int j = __ffs(actj) - 1;
      actj &= actj - 1;
      int id = __shfl(id0, j);
      float f = feats[(size_t)id*DIN + lane];
      #pragma unroll
      for (int k = 0; k < KP; ++k) acc[k] += h_lds[w][j][k] * f;
    }
  }
  if (n < M_PAD) {
    size_t base = (size_t)n*KDIM;
    #pragma unroll
    for (int k = 0; k < KP; ++k)
      g[base + k*DIN + lane] = __float2bfloat16(acc[k]);
  }
}

// ---------------- Kernel 2: 128x128 BK=64 MFMA GEMM + fused pool -------------
// Conservative sync (stage -> sync -> compute -> sync), 3 blocks/CU.
// LDS rows are 128B (64 bf16) split into 8 chunks of 16B; chunk XOR-swizzled
// by (row&7): inverse applied to the GLOBAL source (global_load_lds dest must
// be linear), forward applied on ds_read -> 2-way conflicts only (free).
__global__ __launch_bounds__(256) void gemm_mfma_pool(
    const __hip_bfloat16* __restrict__ g, const __hip_bfloat16* __restrict__ Wt,
    const int* __restrict__ batch, float* __restrict__ partial) {
  __shared__ __align__(16) char lA[BM*128];   // 16KB
  __shared__ __align__(16) char lB[BN*128];   // 16KB
  __shared__ float psum[NB][BN];              // 8KB
  __shared__ int bid[BM];
  // XCD-chunked bijective swizzle: hw-consecutive ids round-robin XCDs;
  // give each XCD a contiguous logical range, cb-fastest (A-panel L2 reuse).
  int wg = blockIdx.x;
  int newid = (wg & 7) * (NWG/8) + (wg >> 3);
  int cb = newid & 7, rb = newid >> 3;
  int r0 = rb*BM, c0 = cb*BN;
  int tid = threadIdx.x;
  int lane = tid & 63, w = tid >> 6;
  int wr = w >> 1, wc = w & 1;

  f32x4 acc[4][4] = {};   // rows wr*64+m*16.., cols wc*64+n*16..

  for (int kt = 0; kt < NKT; ++kt) {
    size_t kk0 = (size_t)kt*BK;
    #pragma unroll
    for (int i = 0; i < 4; ++i) {     // A: 128 rows x 8 chunks = 1024
      int e = i*256 + tid;
      int row = e >> 3, c = e & 7;
      int gc = c ^ (row & 7);
      GLD16(g + (size_t)(r0+row)*KDIM + kk0 + gc*8, lA + e*16);
    }
    #pragma unroll
    for (int i = 0; i < 4; ++i) {     // B: 128 rows x 8 chunks
      int e = i*256 + tid;
      int row = e >> 3, c = e & 7;
      int gc = c ^ (row & 7);
      GLD16(Wt + (size_t)(c0+row)*KDIM + kk0 + gc*8, lB + e*16);
    }
    __syncthreads();
    #pragma unroll
    for (int ks = 0; ks < 2; ++ks) {
      bf16x8 af[4], bfr[4];
      #pragma unroll
      for (int m = 0; m < 4; ++m) {
        int row = wr*64 + m*16 + (lane & 15);
        int c = (ks*4 + (lane >> 4)) ^ (row & 7);
        af[m] = *(const bf16x8*)(lA + row*128 + c*16);
      }
      #pragma unroll
      for (int n = 0; n < 4; ++n) {
        int row = wc*64 + n*16 + (lane & 15);
        int c = (ks*4 + (lane >> 4)) ^ (row & 7);
        bfr[n] = *(const bf16x8*)(lB + row*128 + c*16);
      }
      #pragma unroll
      for (int m = 0; m < 4; ++m)
        #pragma unroll
        for (int n = 0; n < 4; ++n)
          acc[m][n] = __builtin_amdgcn_mfma_f32_16x16x32_bf16(af[m], bfr[n], acc[m][n], 0, 0, 0);
    }
    __syncthreads();
  }

  // ---- epilogue: leaky + deterministic per-batch column sums ----
  if (tid < BM) bid[tid] = (r0 + tid < N_PTS) ? batch[r0 + tid] : -1;
  for (int z = tid; z < NB*BN; z += 256) (&psum[0][0])[z] = 0.0f;
  __syncthreads();
  int q = lane >> 4;
  #pragma unroll 1
  for (int phase = 0; phase < 8; ++phase) {
    if (wr*4 + q == phase) {
      #pragma unroll
      for (int n = 0; n < 4; ++n) {
        int c = wc*64 + n*16 + (lane & 15);
        float run = 0.0f; int curb = -2;
        #pragma unroll
        for (int m = 0; m < 4; ++m) {
          #pragma unroll
          for (int j = 0; j < 4; ++j) {
            int r = wr*64 + m*16 + q*4 + j;
            int b = bid[r];
            float v = acc[m][n][j];
            v = v > 0.0f ? v : 0.1f*v;
            if (b != curb) { if (curb >= 0) psum[curb][c] += run; run = 0.0f; curb = b; }
            run += v;
          }
        }
        if (curb >= 0) psum[curb][c] += run;
      }
    }
    __syncthreads();
  }
  for (int z = tid; z < NB*BN; z += 256) {
    int b = z >> 7, c = z & 127;
    partial[((size_t)rb*NB + b)*DOUT + c0 + c] = psum[b][c];
  }
}

// ---------------- Kernel 3: reduce partials -> pooled mean -------------------
__global__ __launch_bounds__(256) void reduce_pool_kernel(
    const float* __restrict__ partial, const int* __restrict__ batch,
    float* __restrict__ pooled) {
  int b = blockIdx.y;
  int c = blockIdx.x*256 + threadIdx.x;
  float s0=0.f, s1=0.f, s2=0.f, s3=0.f;
  int rb = 0;
  for (; rb + 4 <= RBP; rb += 4) {
    s0 += partial[((size_t)(rb+0)*NB + b)*DOUT + c];
    s1 += partial[((size_t)(rb+1)*NB + b)*DOUT + c];
    s2 += partial[((size_t)(rb+2)*NB + b)*DOUT + c];
    s3 += partial[((size_t)(rb+3)*NB + b)*DOUT + c];
  }
  for (; rb < RBP; ++rb) s0 += partial[((size_t)rb*NB + b)*DOUT + c];
  float s = (s0+s1)+(s2+s3);
  int lb, ub;
  { int l = 0, r = N_PTS; while (l < r) { int m = (l+r)>>1; if (batch[m] <  b) l = m+1; else r = m; } lb = l; }
  { int l = 0, r = N_PTS; while (l < r) { int m = (l+r)>>1; if (batch[m] <= b) l = m+1; else r = m; } ub = l; }
  float cnt = (float)(ub - lb);
  pooled[b*DOUT + c] = s / fmaxf(cnt, 1.0f);
}

// ---------------- Kernel 4: fused 3-layer MLP head --------------------------
__global__ __launch_bounds__(512) void mlp_fused_kernel(
    const float* __restrict__ pooled,
    const float* __restrict__ w1, const float* __restrict__ b1,
    const float* __restrict__ w2, const float* __restrict__ b2,
    const float* __restrict__ w3, const float* __restrict__ b3,
    float* __restrict__ out) {
  __shared__ float pl[DOUT];
  __shared__ float hh[512];
  int b = blockIdx.x, o = threadIdx.x;
  for (int i = o; i < DOUT; i += 512) pl[i] = pooled[b*DOUT + i];
  __syncthreads();
  float a = b1[o];
  #pragma unroll 8
  for (int i = 0; i < DOUT; ++i) a += pl[i] * w1[(size_t)i*512 + o];
  hh[o] = fmaxf(a, 0.0f);
  __syncthreads();
  float a2 = 0.0f;
  if (o < 256) {
    a2 = b2[o];
    #pragma unroll 8
    for (int i = 0; i < 512; ++i) a2 += hh[i] * w2[(size_t)i*256 + o];
  }
  __syncthreads();
  if (o < 256) pl[o] = fmaxf(a2, 0.0f);
  __syncthreads();
  if (o < 152) {
    float a3 = b3[o];
    #pragma unroll 8
    for (int i = 0; i < 256; ++i) a3 += pl[i] * w3[i*152 + o];
    out[b*152 + o] = a3;
  }
}

// ---------------- launch -----------------------------------------------------
extern "C" void kernel_launch(void* const* d_in, const int* in_sizes, int n_in,
                              void* d_out, int out_size, void* d_ws, size_t ws_size,
                              hipStream_t stream) {
  (void)in_sizes; (void)n_in; (void)out_size; (void)ws_size;
  const float* pos   = (const float*)d_in[0];
  const float* feats = (const float*)d_in[1];
  const float* kpts  = (const float*)d_in[2];
  const float* kpw   = (const float*)d_in[3];
  const float* w1    = (const float*)d_in[4];
  const float* b1    = (const float*)d_in[5];
  const float* w2    = (const float*)d_in[6];
  const float* b2    = (const float*)d_in[7];
  const float* w3    = (const float*)d_in[8];
  const float* b3    = (const float*)d_in[9];
  const int* nidx    = (const int*)d_in[10];
  const int* batch   = (const int*)d_in[11];
  float* out = (float*)d_out;

  char* ws = (char*)d_ws;
  const size_t off_g       = 0;                          // 50176*960*2   = 96,337,920
  const size_t off_wt      = 96337920;                   // 1024*960*2    = 1,966,080
  const size_t off_partial = off_wt + 1966080;           // 392*16*1024*4 = 25,690,112
  const size_t off_pooled  = off_partial + 25690112;     // 65,536
  __hip_bfloat16* g  = (__hip_bfloat16*)(ws + off_g);
  __hip_bfloat16* wt = (__hip_bfloat16*)(ws + off_wt);
  float* partial = (float*)(ws + off_partial);
  float* pooled  = (float*)(ws + off_pooled);

  wt_kernel<<<dim3(KDIM/64, DOUT/64), 256, 0, stream>>>(kpw, wt);
  kpconv_wave_kernel<<<M_PAD/4, 256, 0, stream>>>(pos, feats, kpts, nidx, g);
  gemm_mfma_pool<<<NWG, 256, 0, stream>>>(g, wt, batch, partial);
  reduce_pool_kernel<<<dim3(DOUT/256, NB), 256, 0, stream>>>(partial, batch, pooled);
  mlp_fused_kernel<<<NB, 512, 0, stream>>>(pooled, w1, b1, w2, b2, w3, b3, out);
}

// Round 6
// 391.900 us; speedup vs baseline: 1.0747x; 1.0032x over previous
//
#include <hip/hip_runtime.h>
#include <hip/hip_bf16.h>

#define N_PTS 50000
#define NNB   32
#define KP    15
#define DIN   64
#define DOUT  1024
#define KDIM  (KP*DIN)    // 960
#define NB    16
#define SIGMA_INV (1.0f/0.3f)

#define BM 256
#define BN 256
#define BK 64
#define NKT (KDIM/BK)              // 15
#define RB ((N_PTS + BM - 1)/BM)   // 196
#define M_PAD (RB*BM)              // 50176
#define NCB (DOUT/BN)              // 4
#define NWG (RB*NCB)               // 784, %8 == 0

typedef __attribute__((ext_vector_type(8))) short bf16x8;
typedef __attribute__((ext_vector_type(4))) float f32x4;

#define GLD16(gsrc, ldst) \
  __builtin_amdgcn_global_load_lds((const __attribute__((address_space(1))) char*)(gsrc), \
                                   (__attribute__((address_space(3))) char*)(ldst), 16, 0, 0)

// ---------------- Kernel 0: W [960][1024] f32 -> Wt [1024][960] bf16 ---------
__global__ __launch_bounds__(256) void wt_kernel(
    const float* __restrict__ W, __hip_bfloat16* __restrict__ Wt) {
  __shared__ float t[64][65];
  int k0 = blockIdx.x * 64;
  int o0 = blockIdx.y * 64;
  int tx = threadIdx.x & 63, ty = threadIdx.x >> 6;
  for (int r = ty; r < 64; r += 4) t[r][tx] = W[(size_t)(k0 + r)*DOUT + o0 + tx];
  __syncthreads();
  for (int r = ty; r < 64; r += 4)
    Wt[(size_t)(o0 + r)*KDIM + k0 + tx] = __float2bfloat16(t[tx][r]);
}

// ---------------- Kernel 1: KPConv g rows, one WAVE per point ---------------
__global__ __launch_bounds__(256) void kpconv_wave_kernel(
    const float* __restrict__ pos, const float* __restrict__ feats,
    const float* __restrict__ kpts, const int* __restrict__ nidx,
    __hip_bfloat16* __restrict__ g) {
  __shared__ float h_lds[4][NNB][16];
  int tid = threadIdx.x;
  int w = tid >> 6, lane = tid & 63;
  int n = blockIdx.x * 4 + w;
  float acc[KP];
  #pragma unroll
  for (int k = 0; k < KP; ++k) acc[k] = 0.0f;

  if (n < N_PTS) {
    int myj = lane & 31;
    int id0 = nidx[n*NNB + myj];
    float px = pos[n*3+0], py = pos[n*3+1], pz = pos[n*3+2];
    float rx = pos[id0*3+0] - px;
    float ry = pos[id0*3+1] - py;
    float rz = pos[id0*3+2] - pz;
    bool anyact = false;
    int khalf = lane >> 5;
    #pragma unroll
    for (int i = 0; i < 8; ++i) {
      int k = 2*i + khalf;
      if (k < KP) {
        float dx = rx - kpts[k*3+0];
        float dy = ry - kpts[k*3+1];
        float dz = rz - kpts[k*3+2];
        float d = sqrtf(dx*dx + dy*dy + dz*dz);
        float h = 1.0f - d * SIGMA_INV;
        h = h > 0.0f ? h : 0.0f;
        h_lds[w][myj][k] = h;
        anyact |= (h > 0.0f);
      }
    }
    unsigned long long bal = __ballot(anyact);
    unsigned int actj = (unsigned int)(bal | (bal >> 32));
    while (actj) {
      int j = __ffs(actj) - 1;
      actj &= actj - 1;
      int id = __shfl(id0, j);
      float f = feats[(size_t)id*DIN + lane];
      #pragma unroll
      for (int k = 0; k < KP; ++k) acc[k] += h_lds[w][j][k] * f;
    }
  }
  if (n < M_PAD) {
    size_t base = (size_t)n*KDIM;
    #pragma unroll
    for (int k = 0; k < KP; ++k)
      g[base + k*DIN + lane] = __float2bfloat16(acc[k]);
  }
}

// ---------------- Kernel 2: 256x256 BK=64 pipelined MFMA GEMM + pool ---------
// Pipeline trick: stage(t+2 -> buf t&1) is issued AFTER the per-iter
// __syncthreads(). The barrier's implicit vmcnt(0) drain only waits on
// tile t+1's loads, which were issued one full compute phase ago (~free).
// Loads for t+2 stay in flight across the entire next compute phase.
// Race-free: writes to buf b are issued only after the barrier at which
// every wave finished reading buf b; residency of t+1 is guaranteed by the
// same barrier's drain. LDS chunk-XOR swizzle (verified conflict-free in R5)
// applied inverse-on-global-source / forward-on-ds_read (rule #21).
__global__ __launch_bounds__(512, 2) void gemm256_pool(
    const __hip_bfloat16* __restrict__ g, const __hip_bfloat16* __restrict__ Wt,
    const int* __restrict__ batch, float* __restrict__ partial) {
  __shared__ __align__(16) char lds[2*65536];   // buf: [A 32KB | B 32KB]
  __shared__ float psum[NB][BN];                // 16KB
  __shared__ int bid[BM];
  int wg = blockIdx.x;
  int newid = (wg & 7)*(NWG/8) + (wg >> 3);     // XCD-chunked bijective swizzle
  int cb = newid & 3, rb = newid >> 2;
  int r0 = rb*BM, c0 = cb*BN;
  int tid = threadIdx.x;
  int lane = tid & 63, w = tid >> 6;
  int wr = w >> 2, wc = w & 3;                  // 2 x 4 waves, 128x64 out each

  f32x4 acc[8][4] = {};

  // stage one K-tile (256 rows x 64 k, A and B) = 8 GLD16 per thread
  #define STAGE(kt, buf) do {                                                  \
    char* dA = lds + (buf)*65536;                                              \
    char* dB = dA + 32768;                                                     \
    size_t kk0 = (size_t)(kt)*BK;                                              \
    _Pragma("unroll")                                                          \
    for (int i = 0; i < 4; ++i) {                                              \
      int e = i*512 + tid;                                                     \
      int row = e >> 3, c = e & 7;                                             \
      int gc = c ^ (row & 7);                                                  \
      GLD16(g + (size_t)(r0+row)*KDIM + kk0 + gc*8, dA + e*16);                \
    }                                                                          \
    _Pragma("unroll")                                                          \
    for (int i = 0; i < 4; ++i) {                                              \
      int e = i*512 + tid;                                                     \
      int row = e >> 3, c = e & 7;                                             \
      int gc = c ^ (row & 7);                                                  \
      GLD16(Wt + (size_t)(c0+row)*KDIM + kk0 + gc*8, dB + e*16);               \
    }                                                                          \
  } while (0)

  STAGE(0, 0);
  STAGE(1, 1);
  if (tid < BM) bid[tid] = (r0 + tid < N_PTS) ? batch[r0 + tid] : -1;
  for (int z = tid; z < NB*BN; z += 512) (&psum[0][0])[z] = 0.0f;
  __syncthreads();   // drains both prologue tiles (one-time cost)

  for (int kt = 0; kt < NKT; ++kt) {
    const char* A = lds + (kt & 1)*65536;
    const char* B = A + 32768;
    #pragma unroll
    for (int ks = 0; ks < 2; ++ks) {
      bf16x8 af[8], bfr[4];
      #pragma unroll
      for (int m = 0; m < 8; ++m) {
        int row = wr*128 + m*16 + (lane & 15);
        int c = (ks*4 + (lane >> 4)) ^ (row & 7);
        af[m] = *(const bf16x8*)(A + row*128 + c*16);
      }
      #pragma unroll
      for (int n = 0; n < 4; ++n) {
        int row = wc*64 + n*16 + (lane & 15);
        int c = (ks*4 + (lane >> 4)) ^ (row & 7);
        bfr[n] = *(const bf16x8*)(B + row*128 + c*16);
      }
      #pragma unroll
      for (int m = 0; m < 8; ++m)
        #pragma unroll
        for (int n = 0; n < 4; ++n)
          acc[m][n] = __builtin_amdgcn_mfma_f32_16x16x32_bf16(af[m], bfr[n], acc[m][n], 0, 0, 0);
    }
    __syncthreads();                          // drains tile kt+1 (old) + syncs reads of buf kt&1
    if (kt + 2 < NKT) STAGE(kt + 2, kt & 1);  // issue-only; in flight across next compute
  }

  // ---- epilogue: leaky + deterministic per-batch column sums ----
  int q = lane >> 4;
  #pragma unroll 1
  for (int phase = 0; phase < 8; ++phase) {
    if (wr*4 + q == phase) {
      #pragma unroll
      for (int n = 0; n < 4; ++n) {
        int c = wc*64 + n*16 + (lane & 15);
        float run = 0.0f; int curb = -2;
        #pragma unroll
        for (int m = 0; m < 8; ++m) {
          #pragma unroll
          for (int j = 0; j < 4; ++j) {
            int r = wr*128 + m*16 + q*4 + j;
            int b = bid[r];
            float v = acc[m][n][j];
            v = v > 0.0f ? v : 0.1f*v;
            if (b != curb) { if (curb >= 0) psum[curb][c] += run; run = 0.0f; curb = b; }
            run += v;
          }
        }
        if (curb >= 0) psum[curb][c] += run;
      }
    }
    __syncthreads();
  }
  for (int z = tid; z < NB*BN; z += 512) {
    int b = z >> 8, c = z & 255;
    partial[((size_t)rb*NB + b)*DOUT + c0 + c] = psum[b][c];
  }
}

// ---------------- Kernel 3: reduce partials -> pooled mean -------------------
__global__ __launch_bounds__(256) void reduce_pool_kernel(
    const float* __restrict__ partial, const int* __restrict__ batch,
    float* __restrict__ pooled) {
  int b = blockIdx.y;
  int c = blockIdx.x*256 + threadIdx.x;
  float s0=0.f, s1=0.f, s2=0.f, s3=0.f;
  int rb = 0;
  for (; rb + 4 <= RB; rb += 4) {
    s0 += partial[((size_t)(rb+0)*NB + b)*DOUT + c];
    s1 += partial[((size_t)(rb+1)*NB + b)*DOUT + c];
    s2 += partial[((size_t)(rb+2)*NB + b)*DOUT + c];
    s3 += partial[((size_t)(rb+3)*NB + b)*DOUT + c];
  }
  for (; rb < RB; ++rb) s0 += partial[((size_t)rb*NB + b)*DOUT + c];
  float s = (s0+s1)+(s2+s3);
  int lb, ub;
  { int l = 0, r = N_PTS; while (l < r) { int m = (l+r)>>1; if (batch[m] <  b) l = m+1; else r = m; } lb = l; }
  { int l = 0, r = N_PTS; while (l < r) { int m = (l+r)>>1; if (batch[m] <= b) l = m+1; else r = m; } ub = l; }
  float cnt = (float)(ub - lb);
  pooled[b*DOUT + c] = s / fmaxf(cnt, 1.0f);
}

// ---------------- Kernel 4: fused 3-layer MLP head --------------------------
__global__ __launch_bounds__(512) void mlp_fused_kernel(
    const float* __restrict__ pooled,
    const float* __restrict__ w1, const float* __restrict__ b1,
    const float* __restrict__ w2, const float* __restrict__ b2,
    const float* __restrict__ w3, const float* __restrict__ b3,
    float* __restrict__ out) {
  __shared__ float pl[DOUT];
  __shared__ float hh[512];
  int b = blockIdx.x, o = threadIdx.x;
  for (int i = o; i < DOUT; i += 512) pl[i] = pooled[b*DOUT + i];
  __syncthreads();
  float a = b1[o];
  #pragma unroll 8
  for (int i = 0; i < DOUT; ++i) a += pl[i] * w1[(size_t)i*512 + o];
  hh[o] = fmaxf(a, 0.0f);
  __syncthreads();
  float a2 = 0.0f;
  if (o < 256) {
    a2 = b2[o];
    #pragma unroll 8
    for (int i = 0; i < 512; ++i) a2 += hh[i] * w2[(size_t)i*256 + o];
  }
  __syncthreads();
  if (o < 256) pl[o] = fmaxf(a2, 0.0f);
  __syncthreads();
  if (o < 152) {
    float a3 = b3[o];
    #pragma unroll 8
    for (int i = 0; i < 256; ++i) a3 += pl[i] * w3[i*152 + o];
    out[b*152 + o] = a3;
  }
}

// ---------------- launch -----------------------------------------------------
extern "C" void kernel_launch(void* const* d_in, const int* in_sizes, int n_in,
                              void* d_out, int out_size, void* d_ws, size_t ws_size,
                              hipStream_t stream) {
  (void)in_sizes; (void)n_in; (void)out_size; (void)ws_size;
  const float* pos   = (const float*)d_in[0];
  const float* feats = (const float*)d_in[1];
  const float* kpts  = (const float*)d_in[2];
  const float* kpw   = (const float*)d_in[3];
  const float* w1    = (const float*)d_in[4];
  const float* b1    = (const float*)d_in[5];
  const float* w2    = (const float*)d_in[6];
  const float* b2    = (const float*)d_in[7];
  const float* w3    = (const float*)d_in[8];
  const float* b3    = (const float*)d_in[9];
  const int* nidx    = (const int*)d_in[10];
  const int* batch   = (const int*)d_in[11];
  float* out = (float*)d_out;

  char* ws = (char*)d_ws;
  const size_t off_g       = 0;                          // 50176*960*2   = 96,337,920
  const size_t off_wt      = 96337920;                   // 1024*960*2    = 1,966,080
  const size_t off_partial = off_wt + 1966080;           // 196*16*1024*4 = 12,845,056
  const size_t off_pooled  = off_partial + 12845056;     // 65,536
  __hip_bfloat16* g  = (__hip_bfloat16*)(ws + off_g);
  __hip_bfloat16* wt = (__hip_bfloat16*)(ws + off_wt);
  float* partial = (float*)(ws + off_partial);
  float* pooled  = (float*)(ws + off_pooled);

  wt_kernel<<<dim3(KDIM/64, DOUT/64), 256, 0, stream>>>(kpw, wt);
  kpconv_wave_kernel<<<M_PAD/4, 256, 0, stream>>>(pos, feats, kpts, nidx, g);
  gemm256_pool<<<NWG, 512, 0, stream>>>(g, wt, batch, partial);
  reduce_pool_kernel<<<dim3(DOUT/256, NB), 256, 0, stream>>>(partial, batch, pooled);
  mlp_fused_kernel<<<NB, 512, 0, stream>>>(pooled, w1, b1, w2, b2, w3, b3, out);
}